// Round 11
// baseline (75.125 us; speedup 1.0000x reference)
//
#include <hip/hip_runtime.h>

// Problem constants (setup_inputs: [16, 3, 512, 512] fp32)
#define HW       262144     // 512*512
#define HWV      65536      // HW/4: float4 vecs per channel-image
#define CH       HW         // channel stride (elements)
#define BSTRIDE  (3*HW)     // batch stride (elements)
#define NELEM_INV (1.0f / 12582912.0f)   // 1 / (16*3*512*512)

#define GRID1    4096
#define BLOCK1   256        // 4096*256*1 vec = NVEC exactly; 256 | HWV -> no image straddle

#define FIXSCALE   68719476736.0   // 2^36 fixed-point scale for deterministic i64 sum
#define FIXSCALE_I (1.0 / 68719476736.0)

typedef float f4 __attribute__((ext_vector_type(4)));
typedef float f2 __attribute__((ext_vector_type(2)));

__device__ __forceinline__ f4 vload(const float* p) {
    return *reinterpret_cast<const f4*>(p);   // global_load_dwordx4 (cached)
}

// f(t) on a packed {pred, tgt} pair. Vector mul/fma -> v_pk_* ; trans scalar.
__device__ __forceinline__ f2 f_lab2(f2 t) {
    const float T0 = 0.008856f;
    f2 lg;
    lg.x = __builtin_amdgcn_logf(t.x);          // log2; log(0)=-inf discarded by select
    lg.y = __builtin_amdgcn_logf(t.y);
    f2 e = lg * 0.33333333333333f;
    f2 cb;
    cb.x = __builtin_amdgcn_exp2f(e.x);         // cbrt(t) = exp2(log2(t)/3)
    cb.y = __builtin_amdgcn_exp2f(e.y);
    f2 lin = __builtin_elementwise_fma(f2{7.787f, 7.787f}, t,
                                       f2{16.0f / 116.0f, 16.0f / 116.0f});
    f2 r;
    r.x = (t.x > T0) ? cb.x : lin.x;
    r.y = (t.y > T0) ? cb.y : lin.y;
    return r;
}

// r,g,b packed {pred, tgt}. /XN,/ZN folded into matrix. L-branch removed:
// 116*f(y)-16 == 903.292*y on the linear branch (ref 903.3; diff ~1e-9 on loss),
// so L/100 = 1.16*f(y)-0.16 uniformly and dL = 1.16*(fy_p - fy_t).
__device__ __forceinline__ float pix_loss2(f2 r, f2 g, f2 b) {
    f2 x = __builtin_elementwise_fma(f2{0.433953f, 0.433953f}, r,
           __builtin_elementwise_fma(f2{0.376219f, 0.376219f}, g, b * 0.189828f));
    f2 y = __builtin_elementwise_fma(f2{0.212671f, 0.212671f}, r,
           __builtin_elementwise_fma(f2{0.715160f, 0.715160f}, g, b * 0.072169f));
    f2 z = __builtin_elementwise_fma(f2{0.017758f, 0.017758f}, r,
           __builtin_elementwise_fma(f2{0.109477f, 0.109477f}, g, b * 0.872766f));
    f2 fx = f_lab2(x);
    f2 fy = f_lab2(y);
    f2 fz = f_lab2(z);
    float u = fx.x - fx.y;        // fx_pred - fx_tgt
    float v = fy.x - fy.y;
    float w = fz.x - fz.y;
    float dL = 1.16f * v;
    float da = (u - v) * (500.0f / 255.0f);
    float db = (v - w) * (200.0f / 255.0f);
    return fmaf(dL, dL, fmaf(da, da, db * db));
}

__device__ __forceinline__ float quad_loss(const f4& pr, const f4& pg, const f4& pb,
                                           const f4& tr, const f4& tg, const f4& tb) {
    float a;
    a  = pix_loss2(f2{pr.x, tr.x}, f2{pg.x, tg.x}, f2{pb.x, tb.x});
    a += pix_loss2(f2{pr.y, tr.y}, f2{pg.y, tg.y}, f2{pb.y, tb.y});
    a += pix_loss2(f2{pr.z, tr.z}, f2{pg.z, tg.z}, f2{pb.z, tb.z});
    a += pix_loss2(f2{pr.w, tr.w}, f2{pg.w, tg.w}, f2{pb.w, tb.w});
    return a;
}

// Fused: per-block fixed-point atomicAdd (deterministic: integer adds are
// associative) + ticket; last block finalizes. NO __threadfence anywhere —
// all cross-block data flows through device-scope atomics (R4's fence-induced
// L2-writeback storm is avoided).
__global__ __launch_bounds__(BLOCK1, 8) void cc_fused(
        const float* __restrict__ pred,
        const float* __restrict__ tgt,
        unsigned long long* __restrict__ acc,   // d_ws + 0
        unsigned* __restrict__ ticket,          // d_ws + 128
        float* __restrict__ out) {
    const int vbase = blockIdx.x << 8;
    const int batch = vbase >> 16;                     // vbase / HWV (uniform per block)
    const size_t ebase = (size_t)batch * BSTRIDE + (size_t)((vbase & (HWV - 1)) << 2);

    const float* pp = pred + ebase + (threadIdx.x << 2);
    const float* tp = tgt  + ebase + (threadIdx.x << 2);

    const f4 pr = vload(pp);
    const f4 pg = vload(pp + CH);
    const f4 pb = vload(pp + 2 * CH);
    const f4 tr = vload(tp);
    const f4 tg = vload(tp + CH);
    const f4 tb = vload(tp + 2 * CH);

    float a = quad_loss(pr, pg, pb, tr, tg, tb);

    // wave (64-lane) shuffle reduce
    #pragma unroll
    for (int off = 32; off > 0; off >>= 1)
        a += __shfl_down(a, off);

    __shared__ float smem[BLOCK1 / 64];
    const int lane = threadIdx.x & 63;
    const int wid  = threadIdx.x >> 6;
    if (lane == 0) smem[wid] = a;
    __syncthreads();

    if (threadIdx.x == 0) {
        float s = 0.0f;
        #pragma unroll
        for (int w = 0; w < BLOCK1 / 64; ++w) s += smem[w];

        // Exact fixed-point quantization in double: err <= 0.5*2^-36 per block.
        unsigned long long q = (unsigned long long)(long long)llrint((double)s * FIXSCALE);
        unsigned long long old = atomicAdd(acc, q);     // returning form (sc0)
        // Ensure the acc-add has been performed at the atomic point before the
        // ticket-add issues (two independent vmem ops could otherwise retire
        // out of order). "memory" clobber pins the ticket atomic after this.
        asm volatile("s_waitcnt vmcnt(0)" :: "v"(old) : "memory");

        unsigned told = atomicAdd(ticket, 1u);
        if (told == GRID1 - 1) {
            // All GRID1 acc-adds happened-before their ticket-adds -> total is complete.
            unsigned long long tot = atomicAdd(acc, 0ULL);   // coherent read
            out[0] = (float)((double)tot * FIXSCALE_I * (double)NELEM_INV);  // WEIGHT=1.0
        }
    }
}

extern "C" void kernel_launch(void* const* d_in, const int* in_sizes, int n_in,
                              void* d_out, int out_size, void* d_ws, size_t ws_size,
                              hipStream_t stream) {
    const float* pred = (const float*)d_in[0];
    const float* tgt  = (const float*)d_in[1];
    float* out = (float*)d_out;

    unsigned long long* acc = (unsigned long long*)d_ws;      // offset 0
    unsigned* ticket = (unsigned*)((char*)d_ws + 128);        // own cacheline

    (void)hipMemsetAsync(d_ws, 0, 136, stream);               // zero acc + ticket (graph memset node)
    cc_fused<<<GRID1, BLOCK1, 0, stream>>>(pred, tgt, acc, ticket, out);
}

// Round 12
// 22.748 us; speedup vs baseline: 3.3025x; 3.3025x over previous
//
#include <hip/hip_runtime.h>

// Problem constants (setup_inputs: [16, 3, 512, 512] fp32)
#define HW       262144     // 512*512
#define HWV      65536      // HW/4: float4 vecs per channel-image
#define CH       HW         // channel stride (elements)
#define BSTRIDE  (3*HW)     // batch stride (elements)
#define NELEM_INV (1.0f / 12582912.0f)   // 1 / (16*3*512*512)

#define GRID1    1024
#define BLOCK1   1024       // 1024*1024*1 vec = NVEC exactly; 1024 | HWV -> no image straddle

typedef float f4 __attribute__((ext_vector_type(4)));
typedef float f2 __attribute__((ext_vector_type(2)));

__device__ __forceinline__ f4 vload(const float* p) {
    return *reinterpret_cast<const f4*>(p);   // global_load_dwordx4 (cached)
}

// f(t) on a packed {pred, tgt} pair. Vector mul/fma -> v_pk_* ; trans scalar.
__device__ __forceinline__ f2 f_lab2(f2 t) {
    const float T0 = 0.008856f;
    f2 lg;
    lg.x = __builtin_amdgcn_logf(t.x);          // log2; log(0)=-inf discarded by select
    lg.y = __builtin_amdgcn_logf(t.y);
    f2 e = lg * 0.33333333333333f;
    f2 cb;
    cb.x = __builtin_amdgcn_exp2f(e.x);         // cbrt(t) = exp2(log2(t)/3)
    cb.y = __builtin_amdgcn_exp2f(e.y);
    f2 lin = __builtin_elementwise_fma(f2{7.787f, 7.787f}, t,
                                       f2{16.0f / 116.0f, 16.0f / 116.0f});
    f2 r;
    r.x = (t.x > T0) ? cb.x : lin.x;
    r.y = (t.y > T0) ? cb.y : lin.y;
    return r;
}

// r,g,b packed {pred, tgt}. /XN,/ZN folded into matrix. L-branch removed:
// 116*f(y)-16 == 903.292*y on the linear branch (ref 903.3; diff ~1e-9 on loss),
// so L/100 = 1.16*f(y)-0.16 uniformly and dL = 1.16*(fy_p - fy_t).
__device__ __forceinline__ float pix_loss2(f2 r, f2 g, f2 b) {
    f2 x = __builtin_elementwise_fma(f2{0.433953f, 0.433953f}, r,
           __builtin_elementwise_fma(f2{0.376219f, 0.376219f}, g, b * 0.189828f));
    f2 y = __builtin_elementwise_fma(f2{0.212671f, 0.212671f}, r,
           __builtin_elementwise_fma(f2{0.715160f, 0.715160f}, g, b * 0.072169f));
    f2 z = __builtin_elementwise_fma(f2{0.017758f, 0.017758f}, r,
           __builtin_elementwise_fma(f2{0.109477f, 0.109477f}, g, b * 0.872766f));
    f2 fx = f_lab2(x);
    f2 fy = f_lab2(y);
    f2 fz = f_lab2(z);
    float u = fx.x - fx.y;        // fx_pred - fx_tgt
    float v = fy.x - fy.y;
    float w = fz.x - fz.y;
    float dL = 1.16f * v;
    float da = (u - v) * (500.0f / 255.0f);
    float db = (v - w) * (200.0f / 255.0f);
    return fmaf(dL, dL, fmaf(da, da, db * db));
}

__device__ __forceinline__ float quad_loss(const f4& pr, const f4& pg, const f4& pb,
                                           const f4& tr, const f4& tg, const f4& tb) {
    float a;
    a  = pix_loss2(f2{pr.x, tr.x}, f2{pg.x, tg.x}, f2{pb.x, tb.x});
    a += pix_loss2(f2{pr.y, tr.y}, f2{pg.y, tg.y}, f2{pb.y, tb.y});
    a += pix_loss2(f2{pr.z, tr.z}, f2{pg.z, tg.z}, f2{pb.z, tb.z});
    a += pix_loss2(f2{pr.w, tr.w}, f2{pg.w, tg.w}, f2{pb.w, tb.w});
    return a;
}

// 4x coarser grid than R9: tests whether per-workgroup dispatch/tail overhead
// is the residual above the read floor. Same per-thread instruction stream.
__global__ __launch_bounds__(BLOCK1, 8) void cc_partial(
        const float* __restrict__ pred,
        const float* __restrict__ tgt,
        float* __restrict__ part) {
    // Block b owns vec range [b*1024, b*1024+1024) — one f4 vec per thread.
    const int vbase = blockIdx.x << 10;
    const int batch = vbase >> 16;                     // vbase / HWV (uniform per block)
    const size_t ebase = (size_t)batch * BSTRIDE + (size_t)((vbase & (HWV - 1)) << 2);

    const float* pp = pred + ebase + (threadIdx.x << 2);
    const float* tp = tgt  + ebase + (threadIdx.x << 2);

    const f4 pr = vload(pp);
    const f4 pg = vload(pp + CH);
    const f4 pb = vload(pp + 2 * CH);
    const f4 tr = vload(tp);
    const f4 tg = vload(tp + CH);
    const f4 tb = vload(tp + 2 * CH);

    float acc = quad_loss(pr, pg, pb, tr, tg, tb);

    // wave (64-lane) shuffle reduce
    #pragma unroll
    for (int off = 32; off > 0; off >>= 1)
        acc += __shfl_down(acc, off);

    __shared__ float smem[BLOCK1 / 64];
    const int lane = threadIdx.x & 63;
    const int wid  = threadIdx.x >> 6;
    if (lane == 0) smem[wid] = acc;
    __syncthreads();
    if (threadIdx.x == 0) {
        float s = 0.0f;
        #pragma unroll
        for (int w = 0; w < BLOCK1 / 64; ++w) s += smem[w];
        part[blockIdx.x] = s;
    }
}

__global__ __launch_bounds__(256) void cc_final(
        const float* __restrict__ part,
        float* __restrict__ out) {
    // 1024 partials: thread t sums floats [4t, 4t+4) via one f4 load.
    f4 a0 = vload(part + (threadIdx.x << 2));
    float acc = (a0.x + a0.y) + (a0.z + a0.w);

    #pragma unroll
    for (int off = 32; off > 0; off >>= 1)
        acc += __shfl_down(acc, off);

    __shared__ float smem[4];
    const int lane = threadIdx.x & 63;
    const int wid  = threadIdx.x >> 6;
    if (lane == 0) smem[wid] = acc;
    __syncthreads();
    if (threadIdx.x == 0) {
        float s = smem[0] + smem[1] + smem[2] + smem[3];
        out[0] = s * NELEM_INV;   // WEIGHT = 1.0
    }
}

extern "C" void kernel_launch(void* const* d_in, const int* in_sizes, int n_in,
                              void* d_out, int out_size, void* d_ws, size_t ws_size,
                              hipStream_t stream) {
    const float* pred = (const float*)d_in[0];
    const float* tgt  = (const float*)d_in[1];
    float* out  = (float*)d_out;
    float* part = (float*)d_ws;   // 1024 floats = 4 KiB scratch

    cc_partial<<<GRID1, BLOCK1, 0, stream>>>(pred, tgt, part);
    cc_final<<<1, 256, 0, stream>>>(part, out);
}